// Round 1
// baseline (241.010 us; speedup 1.0000x reference)
//
#include <hip/hip_runtime.h>

// AttentionLoss: out = sum_{valid}(guide * pred) / sum(tl*ml) * 1.0
// guide = 1 - exp(-(n/tl - t/ml)^2 / (2*0.2^2)) = 1 - exp(-12.5*d*d)
// valid: t < ml[b] && n < tl[b]
//
// Shapes: pred [B=64, MEL=2000, TEXT=256] f32; lengths int32 [64].
// Memory-bound: only the valid region (~33 MB avg) is read, coalesced.

#define BB 64
#define MEL_MAX 2000
#define TEXT_MAX 256
#define NBLOCKS 2048

__global__ __launch_bounds__(256) void attn_partial(
    const float* __restrict__ pred,
    const int* __restrict__ text_len,
    const int* __restrict__ mel_len,
    float* __restrict__ partials)
{
    const int lane = threadIdx.x;           // n index, 0..255
    float acc = 0.0f;
    const int nrows = BB * MEL_MAX;
    for (int row = blockIdx.x; row < nrows; row += gridDim.x) {
        const int b = row / MEL_MAX;
        const int t = row - b * MEL_MAX;
        const int mlb = mel_len[b];
        if (t >= mlb) continue;             // whole row invalid: no load
        const int tlb = text_len[b];
        if (lane < tlb) {
            const float inv_tl = 1.0f / (float)tlb;
            const float inv_ml = 1.0f / (float)mlb;
            const float d = (float)lane * inv_tl - (float)t * inv_ml;
            const float guide = 1.0f - __expf(-12.5f * d * d);
            acc += guide * pred[(size_t)row * TEXT_MAX + lane];
        }
    }
    // block reduction: wave64 shuffle then LDS across 4 waves
    for (int off = 32; off > 0; off >>= 1)
        acc += __shfl_down(acc, off, 64);
    __shared__ float s[4];
    const int wid = threadIdx.x >> 6;
    if ((threadIdx.x & 63) == 0) s[wid] = acc;
    __syncthreads();
    if (threadIdx.x == 0)
        partials[blockIdx.x] = s[0] + s[1] + s[2] + s[3];
}

__global__ __launch_bounds__(256) void attn_final(
    const float* __restrict__ partials,
    const int* __restrict__ text_len,
    const int* __restrict__ mel_len,
    float* __restrict__ out)
{
    float acc = 0.0f;
    for (int i = threadIdx.x; i < NBLOCKS; i += 256)
        acc += partials[i];
    for (int off = 32; off > 0; off >>= 1)
        acc += __shfl_down(acc, off, 64);
    __shared__ float s[4];
    const int wid = threadIdx.x >> 6;
    if ((threadIdx.x & 63) == 0) s[wid] = acc;
    __syncthreads();
    if (threadIdx.x == 0) {
        const float loss = s[0] + s[1] + s[2] + s[3];
        float active = 0.0f;
        for (int b = 0; b < BB; b++)
            active += (float)text_len[b] * (float)mel_len[b];
        out[0] = loss / active;  // ATTN_WEIGHT = 1.0
    }
}

extern "C" void kernel_launch(void* const* d_in, const int* in_sizes, int n_in,
                              void* d_out, int out_size, void* d_ws, size_t ws_size,
                              hipStream_t stream)
{
    // inputs: 0 = targets (unused zeros), 1 = predictions, 2 = text_lengths, 3 = mel_lengths
    const float* pred = (const float*)d_in[1];
    const int* tl = (const int*)d_in[2];
    const int* ml = (const int*)d_in[3];
    float* out = (float*)d_out;
    float* partials = (float*)d_ws;   // NBLOCKS floats

    attn_partial<<<NBLOCKS, 256, 0, stream>>>(pred, tl, ml, partials);
    attn_final<<<1, 256, 0, stream>>>(partials, tl, ml, out);
}

// Round 2
// 227.641 us; speedup vs baseline: 1.0587x; 1.0587x over previous
//
#include <hip/hip_runtime.h>

// AttentionLoss: out = sum_{valid}(guide * pred) / sum(tl*ml)
// guide = 1 - exp(-12.5*(n/tl - t/ml)^2);  valid: t < ml[b] && n < tl[b]
// pred [B=64, MEL=2000, TEXT=256] f32; lengths int32 [64].
//
// R1 restructure: one batch per block (lengths hoisted out of the loop),
// one wave per row via float4 (16B/lane), uniform-trip inner loop -> MLP.

#define BB 64
#define MEL_MAX 2000
#define TEXT_MAX 256
#define BLK_PER_B 32
#define NBLOCKS (BB * BLK_PER_B)   // 2048

__global__ __launch_bounds__(256) void attn_partial(
    const float* __restrict__ pred,
    const int* __restrict__ text_len,
    const int* __restrict__ mel_len,
    float* __restrict__ partials)
{
    const int b    = blockIdx.x >> 5;        // 0..63
    const int j    = blockIdx.x & 31;        // 0..31
    const int wave = threadIdx.x >> 6;       // 0..3
    const int lane = threadIdx.x & 63;       // 0..63

    const int mlb = mel_len[b];
    const int tlb = text_len[b];
    const float inv_tl = 1.0f / (float)tlb;
    const float inv_ml = 1.0f / (float)mlb;

    const int n0 = lane << 2;                 // first of 4 text positions
    const float nbase = (float)n0 * inv_tl;
    const bool lane_live = (n0 < tlb);        // any of the 4 elems valid?

    const float* bbase = pred + (size_t)b * MEL_MAX * TEXT_MAX;

    float acc = 0.0f;
    // rows t = j*4 + wave + 128*k, wave-uniform trip count
    for (int t = (j << 2) + wave; t < mlb; t += BLK_PER_B * 4) {
        float4 v;
        if (lane_live)
            v = *(const float4*)(bbase + (size_t)t * TEXT_MAX + n0);
        const float tn = (float)t * inv_ml;
        #pragma unroll
        for (int e = 0; e < 4; e++) {
            const float d = nbase + (float)e * inv_tl - tn;
            const float g = 1.0f - __expf(-12.5f * d * d);
            const float pv = (&v.x)[e];
            acc += (n0 + e < tlb) ? g * pv : 0.0f;
        }
    }

    // block reduction: wave64 shuffle then LDS across 4 waves
    for (int off = 32; off > 0; off >>= 1)
        acc += __shfl_down(acc, off, 64);
    __shared__ float s[4];
    if (lane == 0) s[wave] = acc;
    __syncthreads();
    if (threadIdx.x == 0)
        partials[blockIdx.x] = s[0] + s[1] + s[2] + s[3];
}

__global__ __launch_bounds__(256) void attn_final(
    const float* __restrict__ partials,
    const int* __restrict__ text_len,
    const int* __restrict__ mel_len,
    float* __restrict__ out)
{
    float acc = 0.0f;
    for (int i = threadIdx.x; i < NBLOCKS; i += 256)
        acc += partials[i];
    for (int off = 32; off > 0; off >>= 1)
        acc += __shfl_down(acc, off, 64);
    __shared__ float s[4];
    const int wid = threadIdx.x >> 6;
    if ((threadIdx.x & 63) == 0) s[wid] = acc;
    __syncthreads();
    if (threadIdx.x == 0) {
        const float loss = s[0] + s[1] + s[2] + s[3];
        float active = 0.0f;
        for (int b = 0; b < BB; b++)
            active += (float)text_len[b] * (float)mel_len[b];
        out[0] = loss / active;  // ATTN_WEIGHT = 1.0
    }
}

extern "C" void kernel_launch(void* const* d_in, const int* in_sizes, int n_in,
                              void* d_out, int out_size, void* d_ws, size_t ws_size,
                              hipStream_t stream)
{
    // inputs: 0 = targets (unused zeros), 1 = predictions, 2 = text_lengths, 3 = mel_lengths
    const float* pred = (const float*)d_in[1];
    const int* tl = (const int*)d_in[2];
    const int* ml = (const int*)d_in[3];
    float* out = (float*)d_out;
    float* partials = (float*)d_ws;   // NBLOCKS floats

    attn_partial<<<NBLOCKS, 256, 0, stream>>>(pred, tl, ml, partials);
    attn_final<<<1, 256, 0, stream>>>(partials, tl, ml, out);
}